// Round 1
// baseline (320.457 us; speedup 1.0000x reference)
//
#include <hip/hip_runtime.h>
#include <math.h>

#define DIM    64
#define N_MEM  32
#define N_ITEM 10000
#define HOPS   2
#define BATCH  4096
#define HIST   50

__device__ __forceinline__ float wave_reduce_sum(float v) {
#pragma unroll
    for (int off = 32; off > 0; off >>= 1)
        v += __shfl_xor(v, off, 64);
    return v;
}

// Stage A: one 64-lane wave per item, lane == dim component.
__global__ __launch_bounds__(256) void ripple_stage1(
    const float* __restrict__ entity_emb,
    const float* __restrict__ relation_emb,
    const float* __restrict__ W_w,
    const float* __restrict__ W_b,
    const int*   __restrict__ item_ids,
    const int*   __restrict__ heads,
    const int*   __restrict__ relations,
    const int*   __restrict__ tails,
    float*       __restrict__ acc_out)
{
    const int wave = (blockIdx.x * blockDim.x + threadIdx.x) >> 6;
    const int lane = threadIdx.x & 63;
    if (wave >= N_ITEM) return;
    const int i = wave;

    const float w_h  = W_w[lane];
    const float w_r  = W_w[DIM + lane];
    const float w_t  = W_w[2 * DIM + lane];
    const float bias = W_b[0];

    float acc = entity_emb[(long)item_ids[i] * DIM + lane];

    for (int h = 0; h < HOPS; ++h) {
        const int base = (h * N_ITEM + i) * N_MEM;
        float te_reg[N_MEM];
        float e[N_MEM];
        float sum_e = 0.f;
#pragma unroll
        for (int m = 0; m < N_MEM; ++m) {
            const int hi = heads[base + m];       // wave-uniform -> s_load
            const int ri = relations[base + m];
            const int ti = tails[base + m];
            const float he = entity_emb[(long)hi * DIM + lane];   // coalesced 256B
            const float re = relation_emb[ri * DIM + lane];       // 8KB table, L1
            const float te = entity_emb[(long)ti * DIM + lane];
            te_reg[m] = te;
            const float part  = he * w_h + re * w_r + te * w_t;
            const float logit = wave_reduce_sum(part) + bias;     // broadcast to all lanes
            const float sig   = 1.f / (1.f + __expf(-logit));
            const float ex    = __expf(sig);                      // softmax over (0,1) values: stable
            e[m] = ex;
            sum_e += ex;
        }
        const float inv = 1.f / sum_e;
#pragma unroll
        for (int m = 0; m < N_MEM; ++m)
            acc += (e[m] * inv) * te_reg[m];
    }
    acc_out[i * DIM + lane] = acc;
}

// Stage B: one wave per batch row.
__global__ __launch_bounds__(256) void ripple_stage2(
    const float* __restrict__ entity_emb,
    const int*   __restrict__ records_idx,
    const int*   __restrict__ items,
    const float* __restrict__ acc_buf,
    float*       __restrict__ out)
{
    const int wave = (blockIdx.x * blockDim.x + threadIdx.x) >> 6;
    const int lane = threadIdx.x & 63;
    if (wave >= BATCH) return;
    const int b = wave;

    const int* ridx = records_idx + b * HIST;
    float user = 0.f;
#pragma unroll 5
    for (int j = 0; j < HIST; ++j)
        user += acc_buf[(long)ridx[j] * DIM + lane];   // acc_buf is 2.56MB: L2-hot

    const float pair = entity_emb[(long)items[b] * DIM + lane];
    const float dot  = wave_reduce_sum(user * pair);
    if (lane == 0) out[b] = 1.f / (1.f + __expf(-dot));
}

extern "C" void kernel_launch(void* const* d_in, const int* in_sizes, int n_in,
                              void* d_out, int out_size, void* d_ws, size_t ws_size,
                              hipStream_t stream) {
    const float* entity_emb   = (const float*)d_in[0];
    const float* relation_emb = (const float*)d_in[1];
    const float* W_w          = (const float*)d_in[2];
    const float* W_b          = (const float*)d_in[3];
    const int*   item_ids     = (const int*)d_in[4];
    const int*   heads        = (const int*)d_in[5];
    const int*   relations    = (const int*)d_in[6];
    const int*   tails        = (const int*)d_in[7];
    const int*   records_idx  = (const int*)d_in[8];
    const int*   items        = (const int*)d_in[9];
    float* out = (float*)d_out;

    float* acc_buf = (float*)d_ws;   // N_ITEM * DIM floats = 2.56 MB

    // Stage 1: 10000 waves, 4 waves (256 threads) per block.
    const int blocks1 = (N_ITEM + 3) / 4;
    ripple_stage1<<<blocks1, 256, 0, stream>>>(entity_emb, relation_emb, W_w, W_b,
                                               item_ids, heads, relations, tails,
                                               acc_buf);

    // Stage 2: 4096 waves, 4 per block.
    const int blocks2 = (BATCH + 3) / 4;
    ripple_stage2<<<blocks2, 256, 0, stream>>>(entity_emb, records_idx, items,
                                               acc_buf, out);
}

// Round 2
// 253.491 us; speedup vs baseline: 1.2642x; 1.2642x over previous
//
#include <hip/hip_runtime.h>
#include <math.h>

#define DIM    64
#define N_MEM  32
#define N_ITEM 10000
#define HOPS   2
#define BATCH  4096
#define HIST   50

__device__ __forceinline__ float wave_reduce_sum(float v) {
#pragma unroll
    for (int off = 32; off > 0; off >>= 1)
        v += __shfl_xor(v, off, 64);
    return v;
}

// Stage A: one 64-lane wave per item, lane == dim component.
// Phase-separated: all gathers first (deep MLP), then all reductions,
// then cache-hot te reload for the weighted sum.
__global__ __launch_bounds__(256) void ripple_stage1(
    const float* __restrict__ entity_emb,
    const float* __restrict__ relation_emb,
    const float* __restrict__ W_w,
    const float* __restrict__ W_b,
    const int*   __restrict__ item_ids,
    const int*   __restrict__ heads,
    const int*   __restrict__ relations,
    const int*   __restrict__ tails,
    float*       __restrict__ acc_out)
{
    const int wave = (blockIdx.x * blockDim.x + threadIdx.x) >> 6;
    const int lane = threadIdx.x & 63;
    if (wave >= N_ITEM) return;
    const int i = __builtin_amdgcn_readfirstlane(wave);

    const float w_h  = W_w[lane];
    const float w_r  = W_w[DIM + lane];
    const float w_t  = W_w[2 * DIM + lane];
    const float bias = W_b[0];

    float acc = entity_emb[(size_t)item_ids[i] * DIM + lane];

#pragma unroll
    for (int h = 0; h < HOPS; ++h) {
        const int base = __builtin_amdgcn_readfirstlane((h * N_ITEM + i) * N_MEM);

        // ---- Phase A: 96 independent gathers, FMA-only consumers ----
        float part[N_MEM];
#pragma unroll
        for (int m = 0; m < N_MEM; ++m) {
            const float he = entity_emb[(size_t)heads[base + m] * DIM + lane];
            const float re = relation_emb[relations[base + m] * DIM + lane];
            const float te = entity_emb[(size_t)tails[base + m] * DIM + lane];
            part[m] = he * w_h + re * w_r + te * w_t;
        }

        // ---- Phase B: 32 independent butterfly reductions, no VMEM waits ----
        float e[N_MEM];
        float sum_e = 0.f;
#pragma unroll
        for (int m = 0; m < N_MEM; ++m) {
            const float logit = wave_reduce_sum(part[m]) + bias;
            const float sig   = 1.f / (1.f + __expf(-logit));
            const float exm   = __expf(sig);
            e[m] = exm;
            sum_e += exm;
        }
        const float inv = 1.f / sum_e;

        // ---- Phase C: te reload (L1/L2-hot, no extra HBM) + weighted sum ----
#pragma unroll
        for (int m = 0; m < N_MEM; ++m) {
            const float te = entity_emb[(size_t)tails[base + m] * DIM + lane];
            acc += (e[m] * inv) * te;
        }
    }
    acc_out[i * DIM + lane] = acc;
}

// Stage B: one wave per batch row; all 50 history loads in flight at once.
__global__ __launch_bounds__(256) void ripple_stage2(
    const float* __restrict__ entity_emb,
    const int*   __restrict__ records_idx,
    const int*   __restrict__ items,
    const float* __restrict__ acc_buf,
    float*       __restrict__ out)
{
    const int wave = (blockIdx.x * blockDim.x + threadIdx.x) >> 6;
    const int lane = threadIdx.x & 63;
    if (wave >= BATCH) return;
    const int b = __builtin_amdgcn_readfirstlane(wave);

    const int rbase = __builtin_amdgcn_readfirstlane(b * HIST);
    float user = 0.f;
#pragma unroll
    for (int j = 0; j < HIST; ++j)
        user += acc_buf[(size_t)records_idx[rbase + j] * DIM + lane];

    const float pair = entity_emb[(size_t)items[b] * DIM + lane];
    const float dot  = wave_reduce_sum(user * pair);
    if (lane == 0) out[b] = 1.f / (1.f + __expf(-dot));
}

extern "C" void kernel_launch(void* const* d_in, const int* in_sizes, int n_in,
                              void* d_out, int out_size, void* d_ws, size_t ws_size,
                              hipStream_t stream) {
    const float* entity_emb   = (const float*)d_in[0];
    const float* relation_emb = (const float*)d_in[1];
    const float* W_w          = (const float*)d_in[2];
    const float* W_b          = (const float*)d_in[3];
    const int*   item_ids     = (const int*)d_in[4];
    const int*   heads        = (const int*)d_in[5];
    const int*   relations    = (const int*)d_in[6];
    const int*   tails        = (const int*)d_in[7];
    const int*   records_idx  = (const int*)d_in[8];
    const int*   items        = (const int*)d_in[9];
    float* out = (float*)d_out;

    float* acc_buf = (float*)d_ws;   // N_ITEM * DIM floats = 2.56 MB

    const int blocks1 = (N_ITEM + 3) / 4;   // 4 waves (256 threads) per block
    ripple_stage1<<<blocks1, 256, 0, stream>>>(entity_emb, relation_emb, W_w, W_b,
                                               item_ids, heads, relations, tails,
                                               acc_buf);

    const int blocks2 = (BATCH + 3) / 4;
    ripple_stage2<<<blocks2, 256, 0, stream>>>(entity_emb, records_idx, items,
                                               acc_buf, out);
}

// Round 3
// 229.504 us; speedup vs baseline: 1.3963x; 1.1045x over previous
//
#include <hip/hip_runtime.h>
#include <math.h>

#define DIM    64
#define N_MEM  32
#define N_ITEM 10000
#define HOPS   2
#define BATCH  4096
#define HIST   50

typedef float4 f4;

// Layout: lane = g*16 + p. g = memory-subgroup (4 rows gathered per instr),
// p = float4 position within a 64-float row. One wave instr = 4 rows x 256B.

__global__ __launch_bounds__(256) void ripple_stage1(
    const float* __restrict__ entity_emb,
    const float* __restrict__ relation_emb,
    const float* __restrict__ W_w,
    const float* __restrict__ W_b,
    const int*   __restrict__ item_ids,
    const int*   __restrict__ heads,
    const int*   __restrict__ relations,
    const int*   __restrict__ tails,
    float*       __restrict__ acc_out)
{
    const int wave = (blockIdx.x * blockDim.x + threadIdx.x) >> 6;
    const int lane = threadIdx.x & 63;
    if (wave >= N_ITEM) return;
    const int g = lane >> 4;      // which of 4 memories per load iteration
    const int p = lane & 15;      // float4 slot within the row

    const f4* __restrict__ E4 = (const f4*)entity_emb;
    const f4* __restrict__ R4 = (const f4*)relation_emb;
    const f4* __restrict__ W4 = (const f4*)W_w;

    const f4 wh = W4[p];
    const f4 wr = W4[16 + p];
    const f4 wt = W4[32 + p];
    const float bias = W_b[0];

    f4 acc = {0.f, 0.f, 0.f, 0.f};
    {   // item embedding: credit it to group 0 only (groups are summed at the end)
        const f4 it = E4[(size_t)item_ids[wave] * 16 + p];
        if (g == 0) acc = it;
    }

#pragma unroll
    for (int h = 0; h < HOPS; ++h) {
        const int base = (h * N_ITEM + wave) * N_MEM + g;   // this lane's m = 4k+g

        // ---- Phase A: gather 8x(head,rel,tail) float4 rows, FMA-only consumers ----
        f4    te[8];
        float part[8];
#pragma unroll
        for (int k = 0; k < 8; ++k) {
            const int hi = heads[base + 4 * k];
            const int ri = relations[base + 4 * k];
            const int ti = tails[base + 4 * k];
            const f4 he = E4[(size_t)hi * 16 + p];
            const f4 re = R4[(size_t)ri * 16 + p];
            const f4 t  = E4[(size_t)ti * 16 + p];
            te[k] = t;
            part[k] = he.x * wh.x + he.y * wh.y + he.z * wh.z + he.w * wh.w
                    + re.x * wr.x + re.y * wr.y + re.z * wr.z + re.w * wr.w
                    + t.x  * wt.x + t.y  * wt.y + t.z  * wt.z + t.w  * wt.w;
        }

        // ---- Phase B: 16-lane reduces (4 memories in parallel), sigmoid+exp ----
        float e[8];
        float se = 0.f;
#pragma unroll
        for (int k = 0; k < 8; ++k) {
            float v = part[k];
            v += __shfl_xor(v, 1, 64);
            v += __shfl_xor(v, 2, 64);
            v += __shfl_xor(v, 4, 64);
            v += __shfl_xor(v, 8, 64);
            const float logit = v + bias;
            const float sig   = 1.f / (1.f + __expf(-logit));
            const float ex    = __expf(sig);
            e[k] = ex;
            se += ex;
        }
        se += __shfl_xor(se, 16, 64);   // combine the 4 groups' partial sums
        se += __shfl_xor(se, 32, 64);
        const float inv = 1.f / se;

        // ---- Phase C: weighted tail sum from registers (no re-fetch) ----
#pragma unroll
        for (int k = 0; k < 8; ++k) {
            const float w = e[k] * inv;
            acc.x += w * te[k].x;
            acc.y += w * te[k].y;
            acc.z += w * te[k].z;
            acc.w += w * te[k].w;
        }
    }

    // combine the 4 groups' partial acc vectors
    acc.x += __shfl_xor(acc.x, 16, 64);
    acc.x += __shfl_xor(acc.x, 32, 64);
    acc.y += __shfl_xor(acc.y, 16, 64);
    acc.y += __shfl_xor(acc.y, 32, 64);
    acc.z += __shfl_xor(acc.z, 16, 64);
    acc.z += __shfl_xor(acc.z, 32, 64);
    acc.w += __shfl_xor(acc.w, 16, 64);
    acc.w += __shfl_xor(acc.w, 32, 64);
    if (g == 0) ((f4*)acc_out)[(size_t)wave * 16 + p] = acc;
}

__global__ __launch_bounds__(256) void ripple_stage2(
    const float* __restrict__ entity_emb,
    const int*   __restrict__ records_idx,
    const int*   __restrict__ items,
    const float* __restrict__ acc_buf,
    float*       __restrict__ out)
{
    const int wave = (blockIdx.x * blockDim.x + threadIdx.x) >> 6;
    const int lane = threadIdx.x & 63;
    if (wave >= BATCH) return;
    const int b = wave;
    const int g = lane >> 4;
    const int p = lane & 15;

    const f4* __restrict__ A4 = (const f4*)acc_buf;
    const f4* __restrict__ E4 = (const f4*)entity_emb;

    f4 user = {0.f, 0.f, 0.f, 0.f};
    const int rb = b * HIST;
#pragma unroll
    for (int k = 0; k < 13; ++k) {                 // ceil(50/4)
        const int j  = 4 * k + g;
        const int jc = j < HIST ? j : (HIST - 1);  // clamp: keep load in-bounds
        const float w = j < HIST ? 1.f : 0.f;
        const int idx = records_idx[rb + jc];
        const f4 r = A4[(size_t)idx * 16 + p];
        user.x += w * r.x;
        user.y += w * r.y;
        user.z += w * r.z;
        user.w += w * r.w;
    }
    // combine 4 groups
    user.x += __shfl_xor(user.x, 16, 64);
    user.x += __shfl_xor(user.x, 32, 64);
    user.y += __shfl_xor(user.y, 16, 64);
    user.y += __shfl_xor(user.y, 32, 64);
    user.z += __shfl_xor(user.z, 16, 64);
    user.z += __shfl_xor(user.z, 32, 64);
    user.w += __shfl_xor(user.w, 16, 64);
    user.w += __shfl_xor(user.w, 32, 64);

    const f4 pair = E4[(size_t)items[b] * 16 + p];
    float dot = user.x * pair.x + user.y * pair.y + user.z * pair.z + user.w * pair.w;
    dot += __shfl_xor(dot, 1, 64);
    dot += __shfl_xor(dot, 2, 64);
    dot += __shfl_xor(dot, 4, 64);
    dot += __shfl_xor(dot, 8, 64);
    if (lane == 0) out[b] = 1.f / (1.f + __expf(-dot));
}

extern "C" void kernel_launch(void* const* d_in, const int* in_sizes, int n_in,
                              void* d_out, int out_size, void* d_ws, size_t ws_size,
                              hipStream_t stream) {
    const float* entity_emb   = (const float*)d_in[0];
    const float* relation_emb = (const float*)d_in[1];
    const float* W_w          = (const float*)d_in[2];
    const float* W_b          = (const float*)d_in[3];
    const int*   item_ids     = (const int*)d_in[4];
    const int*   heads        = (const int*)d_in[5];
    const int*   relations    = (const int*)d_in[6];
    const int*   tails        = (const int*)d_in[7];
    const int*   records_idx  = (const int*)d_in[8];
    const int*   items        = (const int*)d_in[9];
    float* out = (float*)d_out;

    float* acc_buf = (float*)d_ws;   // N_ITEM * DIM floats = 2.56 MB

    const int blocks1 = (N_ITEM + 3) / 4;   // 4 waves (256 threads) per block
    ripple_stage1<<<blocks1, 256, 0, stream>>>(entity_emb, relation_emb, W_w, W_b,
                                               item_ids, heads, relations, tails,
                                               acc_buf);

    const int blocks2 = (BATCH + 3) / 4;
    ripple_stage2<<<blocks2, 256, 0, stream>>>(entity_emb, records_idx, items,
                                               acc_buf, out);
}